// Round 7
// baseline (88.012 us; speedup 1.0000x reference)
//
#include <hip/hip_runtime.h>
#include <math.h>

namespace {
constexpr int NB = 2048;      // batch
constexpr int NNODE = 6;      // nodes
constexpr int DD = 2048;      // feature dim
constexpr int HH = 1024;      // hidden
constexpr int CC = 200;       // classes
constexpr int K2 = 2 * DD;    // 4096 (concat dim)
constexpr int NPAD = 256;     // padded class dim
constexpr int ZS2 = 16;       // split-K for gemm2 (K per z = 256)
constexpr float ALPHA_C = 0.015f;
constexpr float SCALE_C = 24.0f;

constexpr int G1_BLOCKS = (K2 / 64) * (NPAD / 64);   // 256
constexpr int BV_BLOCKS = 25;
}

typedef __attribute__((ext_vector_type(8))) short bf16x8;
typedef __attribute__((ext_vector_type(4))) float f32x4;

static __device__ __forceinline__ unsigned short f2bf(float x) {
    union { float f; unsigned int u; } v; v.f = x;
    unsigned int r = v.u + 0x7FFFu + ((v.u >> 16) & 1u);  // RNE
    return (unsigned short)(r >> 16);
}

static __device__ __forceinline__ unsigned pack2(float a, float b) {
    return (unsigned)f2bf(a) | ((unsigned)f2bf(b) << 16);
}

// ---------------------------------------------------------------------------
// Wave-parallel node weights: lane (u*8+v) computes one exp+sqrt; butterfly
// reduce for mean; 8-lane-group reduce for row sums; broadcast s[0..5].
// ---------------------------------------------------------------------------
static __device__ __forceinline__ void compute_s_wave(const float* __restrict__ cdds,
                                                      int b, float sv[NNODE]) {
    const int lane = threadIdx.x & 63;
    const int u = lane >> 3;      // 0..7
    const int v = lane & 7;       // 0..7
    const float* cd = cdds + (size_t)b * 36;
    float w = 0.f;
    const bool valid = (u < 6) & (v < 6) & (u != v);
    if (u < 6 && v < 6 && u != v) {
        float cyu = (cd[u * 6 + 1] + cd[u * 6 + 3]) * 0.5f;
        float cxu = (cd[u * 6 + 2] + cd[u * 6 + 4]) * 0.5f;
        float cyv = (cd[v * 6 + 1] + cd[v * 6 + 3]) * 0.5f;
        float cxv = (cd[v * 6 + 2] + cd[v * 6 + 4]) * 0.5f;
        float dx = cxu - cxv, dy = cyu - cyv;
        w = expf(-ALPHA_C * sqrtf(dx * dx + dy * dy));
    }
    float s = w;
#pragma unroll
    for (int m = 32; m >= 1; m >>= 1) s += __shfl_xor(s, m);
    float mean = s * (1.f / 30.f);
    float tt = valid ? fmaxf(w - mean, 0.f) : 0.f;
    tt += __shfl_xor(tt, 1);
    tt += __shfl_xor(tt, 2);
    tt += __shfl_xor(tt, 4);
    float su = SCALE_C * tt * 0.2f;   // s[u] for this lane's row u
#pragma unroll
    for (int uu = 0; uu < NNODE; ++uu) sv[uu] = __shfl(su, uu * 8);
}

// ---------------------------------------------------------------------------
// k_prep: blocks [0,256): Mt[256][4096] = (fc_w @ cls_w)^T  bf16 MFMA
//         blocks [256,281): bvec[c] = fc_b @ cls_w + cls_b
// ---------------------------------------------------------------------------
__global__ __launch_bounds__(256) void k_prep(const float* __restrict__ fc_w,
                                              const float* __restrict__ cls_w,
                                              const float* __restrict__ fc_b,
                                              const float* __restrict__ cls_b,
                                              unsigned short* __restrict__ Mt,
                                              float* __restrict__ bvec)
{
    __shared__ short As[64][68];
    __shared__ short Bs[64][68];
    __shared__ float red[256];
    const int bx = blockIdx.x;
    const int t = threadIdx.x;

    if (bx >= G1_BLOCKS) {
        // ---------------- bvec ----------------
        const int bb = bx - G1_BLOCKS;    // 0..24
        int c8 = t & 7;
        int hs = t >> 3;
        int c = bb * 8 + c8;              // < 200
        float acc = 0.f;
        for (int h = hs; h < HH; h += 32)
            acc += fc_b[h] * cls_w[(size_t)h * CC + c];
        red[t] = acc;
        __syncthreads();
        for (int s = 128; s >= 8; s >>= 1) {
            if (t < s) red[t] += red[t + s];
            __syncthreads();
        }
        if (t < 8) bvec[c] = red[t] + cls_b[c];
        return;
    }

    // ---------------- gemm1: Mt = (fc_w @ cls_w)^T ----------------
    const int lane = t & 63;
    const int wid = t >> 6;
    const int wm = wid >> 1, wn = wid & 1;
    const int bm = (bx >> 2) * 64;        // over concat dim (4096)
    const int bn = (bx & 3) * 64;         // over class dim (256)

    f32x4 acc[2][2] = {};

    for (int k0 = 0; k0 < HH; k0 += 64) {
        // A tile 64x64: fc_w f32 -> bf16 (coalesced float4)
#pragma unroll
        for (int c = 0; c < 4; ++c) {
            int i = t + c * 256;
            int row = i >> 4;
            int k4 = (i & 15) << 2;
            float4 v = *(const float4*)(fc_w + (size_t)(bm + row) * HH + k0 + k4);
            ushort4 o;
            o.x = f2bf(v.x); o.y = f2bf(v.y); o.z = f2bf(v.z); o.w = f2bf(v.w);
            *(ushort4*)&As[row][k4] = o;
        }
        // B tile: cls_w[k][n] f32, transposed into Bs[n][k]
#pragma unroll
        for (int c = 0; c < 4; ++c) {
            int i = t + c * 256;
            int kr = i >> 4;
            int n4 = (i & 15) << 2;
            const float* sp = cls_w + (size_t)(k0 + kr) * CC + bn + n4;
            float4 v = {0.f, 0.f, 0.f, 0.f};
            if (bn + n4 + 3 < CC) {
                v = *(const float4*)sp;
            } else {
                if (bn + n4 + 0 < CC) v.x = sp[0];
                if (bn + n4 + 1 < CC) v.y = sp[1];
                if (bn + n4 + 2 < CC) v.z = sp[2];
                if (bn + n4 + 3 < CC) v.w = sp[3];
            }
            Bs[n4 + 0][kr] = (short)f2bf(v.x);
            Bs[n4 + 1][kr] = (short)f2bf(v.y);
            Bs[n4 + 2][kr] = (short)f2bf(v.z);
            Bs[n4 + 3][kr] = (short)f2bf(v.w);
        }
        __syncthreads();
#pragma unroll
        for (int ks = 0; ks < 2; ++ks) {
            int kk = ks * 32 + ((lane >> 4) << 3);
            int ar = lane & 15;
            bf16x8 a0 = *(const bf16x8*)&As[wm * 32 + ar][kk];
            bf16x8 a1 = *(const bf16x8*)&As[wm * 32 + 16 + ar][kk];
            bf16x8 b0 = *(const bf16x8*)&Bs[wn * 32 + ar][kk];
            bf16x8 b1 = *(const bf16x8*)&Bs[wn * 32 + 16 + ar][kk];
            acc[0][0] = __builtin_amdgcn_mfma_f32_16x16x32_bf16(a0, b0, acc[0][0], 0, 0, 0);
            acc[0][1] = __builtin_amdgcn_mfma_f32_16x16x32_bf16(a0, b1, acc[0][1], 0, 0, 0);
            acc[1][0] = __builtin_amdgcn_mfma_f32_16x16x32_bf16(a1, b0, acc[1][0], 0, 0, 0);
            acc[1][1] = __builtin_amdgcn_mfma_f32_16x16x32_bf16(a1, b1, acc[1][1], 0, 0, 0);
        }
        __syncthreads();
    }
    // transposed store: Mt[n][m]
#pragma unroll
    for (int fm = 0; fm < 2; ++fm)
#pragma unroll
        for (int fn = 0; fn < 2; ++fn) {
            int gm0 = bm + wm * 32 + fm * 16 + ((lane >> 4) << 2);
            int gn = bn + wn * 32 + fn * 16 + (lane & 15);
            ushort4 o;
            o.x = f2bf(acc[fm][fn][0]); o.y = f2bf(acc[fm][fn][1]);
            o.z = f2bf(acc[fm][fn][2]); o.w = f2bf(acc[fm][fn][3]);
            *(ushort4*)(Mt + (size_t)gn * K2 + gm0) = o;
        }
}

// ---------------------------------------------------------------------------
// k_pq: standalone, zero LDS. pq[b][0:D]=sum_u s*pf, pq[b][D:2D]=sum_u pf.
// grid = NB*2 blocks x 256 threads; thread t covers 4 contiguous floats.
// All 6 row-loads issued as independent temps (stay in flight together).
// ---------------------------------------------------------------------------
__global__ __launch_bounds__(256) void k_pq(const float* __restrict__ pf,
                                            const float* __restrict__ cdds,
                                            unsigned short* __restrict__ pq)
{
    const int bid = blockIdx.x;
    const int b = bid >> 1;
    const int d = ((bid & 1) << 10) + (threadIdx.x << 2);

    const float* base = pf + (size_t)b * NNODE * DD + d;
    // issue all 6 independent loads up front
    float4 v0 = *(const float4*)(base + 0 * DD);
    float4 v1 = *(const float4*)(base + 1 * DD);
    float4 v2 = *(const float4*)(base + 2 * DD);
    float4 v3 = *(const float4*)(base + 3 * DD);
    float4 v4 = *(const float4*)(base + 4 * DD);
    float4 v5 = *(const float4*)(base + 5 * DD);

    // node weights (shuffle chain overlaps load latency)
    float sv[NNODE];
    compute_s_wave(cdds, b, sv);

    float4 q;
    q.x = v0.x + v1.x + v2.x + v3.x + v4.x + v5.x;
    q.y = v0.y + v1.y + v2.y + v3.y + v4.y + v5.y;
    q.z = v0.z + v1.z + v2.z + v3.z + v4.z + v5.z;
    q.w = v0.w + v1.w + v2.w + v3.w + v4.w + v5.w;

    float4 p = {0.f, 0.f, 0.f, 0.f};
    p.x = fmaf(sv[0], v0.x, p.x); p.y = fmaf(sv[0], v0.y, p.y);
    p.z = fmaf(sv[0], v0.z, p.z); p.w = fmaf(sv[0], v0.w, p.w);
    p.x = fmaf(sv[1], v1.x, p.x); p.y = fmaf(sv[1], v1.y, p.y);
    p.z = fmaf(sv[1], v1.z, p.z); p.w = fmaf(sv[1], v1.w, p.w);
    p.x = fmaf(sv[2], v2.x, p.x); p.y = fmaf(sv[2], v2.y, p.y);
    p.z = fmaf(sv[2], v2.z, p.z); p.w = fmaf(sv[2], v2.w, p.w);
    p.x = fmaf(sv[3], v3.x, p.x); p.y = fmaf(sv[3], v3.y, p.y);
    p.z = fmaf(sv[3], v3.z, p.z); p.w = fmaf(sv[3], v3.w, p.w);
    p.x = fmaf(sv[4], v4.x, p.x); p.y = fmaf(sv[4], v4.y, p.y);
    p.z = fmaf(sv[4], v4.z, p.z); p.w = fmaf(sv[4], v4.w, p.w);
    p.x = fmaf(sv[5], v5.x, p.x); p.y = fmaf(sv[5], v5.y, p.y);
    p.z = fmaf(sv[5], v5.z, p.z); p.w = fmaf(sv[5], v5.w, p.w);

    unsigned short* o = pq + (size_t)b * K2;
    ushort4 pb, qb;
    pb.x = f2bf(p.x); pb.y = f2bf(p.y); pb.z = f2bf(p.z); pb.w = f2bf(p.w);
    qb.x = f2bf(q.x); qb.y = f2bf(q.y); qb.z = f2bf(q.z); qb.w = f2bf(q.w);
    *(ushort4*)(o + d) = pb;
    *(ushort4*)(o + DD + d) = qb;
}

// ---------------------------------------------------------------------------
// GEMM2: part[z][2048][256] = pq @ Mt^T partial (bf16 MFMA, split-K=16)
// grid (32, 16) = 512 blocks. Tile 64 x 256, K per z = 256.
// ---------------------------------------------------------------------------
__global__ __launch_bounds__(256) void k_gemm2(const unsigned short* __restrict__ A,
                                               const unsigned short* __restrict__ Bt,
                                               float* __restrict__ part)
{
    __shared__ short As[64][72];    // 9.2 KB
    __shared__ short Bs[256][72];   // 36.9 KB
    const int t = threadIdx.x;
    const int lane = t & 63;
    const int wid = t >> 6;
    const int wr = wid >> 1, wc = wid & 1;
    const int bm = blockIdx.x * 64;
    const int z = blockIdx.y;
    const int kbase = z * (K2 / ZS2);   // 256 per z

    f32x4 acc[2][8] = {};

    for (int k0 = kbase; k0 < kbase + K2 / ZS2; k0 += 64) {
#pragma unroll
        for (int c = 0; c < 2; ++c) {
            int i = t + c * 256;
            int row = i >> 3;
            int k8 = (i & 7) << 3;
            *(uint4*)&As[row][k8] =
                *(const uint4*)(A + (size_t)(bm + row) * K2 + k0 + k8);
        }
#pragma unroll
        for (int c = 0; c < 8; ++c) {
            int i = t + c * 256;
            int n = i >> 3;
            int k8 = (i & 7) << 3;
            *(uint4*)&Bs[n][k8] =
                *(const uint4*)(Bt + (size_t)n * K2 + k0 + k8);
        }
        __syncthreads();
#pragma unroll
        for (int ks = 0; ks < 2; ++ks) {
            int kk = ks * 32 + ((lane >> 4) << 3);
            int ar = lane & 15;
            bf16x8 a0 = *(const bf16x8*)&As[wr * 32 + ar][kk];
            bf16x8 a1 = *(const bf16x8*)&As[wr * 32 + 16 + ar][kk];
#pragma unroll
            for (int fn = 0; fn < 8; ++fn) {
                bf16x8 b = *(const bf16x8*)&Bs[wc * 128 + fn * 16 + ar][kk];
                acc[0][fn] = __builtin_amdgcn_mfma_f32_16x16x32_bf16(a0, b, acc[0][fn], 0, 0, 0);
                acc[1][fn] = __builtin_amdgcn_mfma_f32_16x16x32_bf16(a1, b, acc[1][fn], 0, 0, 0);
            }
        }
        __syncthreads();
    }
#pragma unroll
    for (int fm = 0; fm < 2; ++fm)
#pragma unroll
        for (int fn = 0; fn < 8; ++fn) {
            int gm0 = bm + wr * 32 + fm * 16 + ((lane >> 4) << 2);
            int gn = wc * 128 + fn * 16 + (lane & 15);
#pragma unroll
            for (int r = 0; r < 4; ++r)
                part[((size_t)z * NB + gm0 + r) * NPAD + gn] = acc[fm][fn][r];
        }
}

// ---------------------------------------------------------------------------
// out[b,c] = (sum_z part[z][b][c]) / 6 + bvec[c]
// ---------------------------------------------------------------------------
__global__ __launch_bounds__(256) void k_combine(const float* __restrict__ part,
                                                 const float* __restrict__ bvec,
                                                 float* __restrict__ out)
{
    int idx = blockIdx.x * blockDim.x + threadIdx.x;
    if (idx >= NB * CC) return;
    int b = idx / CC;
    int c = idx - b * CC;
    float s = 0.f;
#pragma unroll
    for (int z = 0; z < ZS2; ++z)
        s += part[((size_t)z * NB + b) * NPAD + c];
    out[idx] = s * (1.f / 6.f) + bvec[c];
}

// ---------------------------------------------------------------------------
extern "C" void kernel_launch(void* const* d_in, const int* in_sizes, int n_in,
                              void* d_out, int out_size, void* d_ws, size_t ws_size,
                              hipStream_t stream)
{
    const float* part_feats = (const float*)d_in[0];
    const float* cdds = (const float*)d_in[1];
    const float* fc_w = (const float*)d_in[2];   // (4096, 1024)
    const float* fc_b = (const float*)d_in[3];   // (1024,)
    const float* cls_w = (const float*)d_in[4];  // (1024, 200)
    const float* cls_b = (const float*)d_in[5];  // (200,)
    float* out = (float*)d_out;                  // (2048, 200)

    char* ws = (char*)d_ws;
    size_t off = 0;
    unsigned short* pq = (unsigned short*)(ws + off); off += (size_t)NB * K2 * 2;        // 16.8 MB
    unsigned short* Mt = (unsigned short*)(ws + off); off += (size_t)NPAD * K2 * 2;      // 2.1 MB
    float* part = (float*)(ws + off);                 off += (size_t)ZS2 * NB * NPAD * 4;// 33.6 MB
    float* bvec = (float*)(ws + off);                 off += 256 * 4;

    // 1. Mt = (fc_w @ cls_w)^T + bvec
    k_prep<<<dim3(G1_BLOCKS + BV_BLOCKS), dim3(256), 0, stream>>>(
        fc_w, cls_w, fc_b, cls_b, Mt, bvec);
    // 2. pq streaming (standalone, zero LDS, full ILP)
    k_pq<<<dim3(NB * 2), dim3(256), 0, stream>>>(part_feats, cdds, pq);
    // 3. pq @ Mt^T partials, split-K=16
    k_gemm2<<<dim3(NB / 64, ZS2), dim3(256), 0, stream>>>(pq, Mt, part);
    // 4. combine + scale + bias
    k_combine<<<dim3((NB * CC + 255) / 256), dim3(256), 0, stream>>>(part, bvec, out);
}

// Round 8
// 69.325 us; speedup vs baseline: 1.2696x; 1.2696x over previous
//
#include <hip/hip_runtime.h>
#include <math.h>

namespace {
constexpr int NB = 2048;      // batch
constexpr int NNODE = 6;      // nodes
constexpr int DD = 2048;      // feature dim
constexpr int HH = 1024;      // hidden
constexpr int CC = 200;       // classes
constexpr int K2 = 2 * DD;    // 4096 (concat dim)
constexpr int NPAD = 256;     // padded class dim
constexpr int ZS1 = 4;        // split-K for g1 (K per z = 256)
constexpr int ZS2 = 16;       // split-K for gemm2 (K per z = 256)
constexpr float ALPHA_C = 0.015f;
constexpr float SCALE_C = 24.0f;
}

typedef __attribute__((ext_vector_type(8))) short bf16x8;
typedef __attribute__((ext_vector_type(4))) float f32x4;

static __device__ __forceinline__ unsigned short f2bf(float x) {
    union { float f; unsigned int u; } v; v.f = x;
    unsigned int r = v.u + 0x7FFFu + ((v.u >> 16) & 1u);  // RNE
    return (unsigned short)(r >> 16);
}

// ---------------------------------------------------------------------------
// Wave-parallel node weights: lane (u*8+v) computes one exp+sqrt; butterfly
// reduce for mean; 8-lane-group reduce for row sums; broadcast s[0..5].
// ---------------------------------------------------------------------------
static __device__ __forceinline__ void compute_s_wave(const float* __restrict__ cdds,
                                                      int b, float sv[NNODE]) {
    const int lane = threadIdx.x & 63;
    const int u = lane >> 3;      // 0..7
    const int v = lane & 7;       // 0..7
    const float* cd = cdds + (size_t)b * 36;
    float w = 0.f;
    const bool valid = (u < 6) & (v < 6) & (u != v);
    if (u < 6 && v < 6 && u != v) {
        float cyu = (cd[u * 6 + 1] + cd[u * 6 + 3]) * 0.5f;
        float cxu = (cd[u * 6 + 2] + cd[u * 6 + 4]) * 0.5f;
        float cyv = (cd[v * 6 + 1] + cd[v * 6 + 3]) * 0.5f;
        float cxv = (cd[v * 6 + 2] + cd[v * 6 + 4]) * 0.5f;
        float dx = cxu - cxv, dy = cyu - cyv;
        w = expf(-ALPHA_C * sqrtf(dx * dx + dy * dy));
    }
    float s = w;
#pragma unroll
    for (int m = 32; m >= 1; m >>= 1) s += __shfl_xor(s, m);
    float mean = s * (1.f / 30.f);
    float tt = valid ? fmaxf(w - mean, 0.f) : 0.f;
    tt += __shfl_xor(tt, 1);
    tt += __shfl_xor(tt, 2);
    tt += __shfl_xor(tt, 4);
    float su = SCALE_C * tt * 0.2f;   // s[u] for this lane's row u
#pragma unroll
    for (int uu = 0; uu < NNODE; ++uu) sv[uu] = __shfl(su, uu * 8);
}

// ---------------------------------------------------------------------------
// k_cvt: cls_w (1024x200 f32) -> cls_wT (256x1024 bf16, transposed, 0-padded)
// 64 blocks: 16 k-tiles x 4 n-tiles of 64x64.
// ---------------------------------------------------------------------------
__global__ __launch_bounds__(256) void k_cvt(const float* __restrict__ cls_w,
                                             unsigned short* __restrict__ cls_wT)
{
    __shared__ float sm[64 * 65];
    const int kt = blockIdx.x & 15;
    const int nt = blockIdx.x >> 4;
    const int t = threadIdx.x;
#pragma unroll
    for (int c = 0; c < 4; ++c) {
        int i = t + c * 256;
        int kr = i >> 4;
        int n4 = (i & 15) << 2;
        int gn = nt * 64 + n4;
        const float* sp = cls_w + (size_t)(kt * 64 + kr) * CC + gn;
        float4 v = {0.f, 0.f, 0.f, 0.f};
        if (gn + 3 < CC) {
            v = *(const float4*)sp;
        } else {
            if (gn + 0 < CC) v.x = sp[0];
            if (gn + 1 < CC) v.y = sp[1];
            if (gn + 2 < CC) v.z = sp[2];
            if (gn + 3 < CC) v.w = sp[3];
        }
        sm[kr * 65 + n4 + 0] = v.x; sm[kr * 65 + n4 + 1] = v.y;
        sm[kr * 65 + n4 + 2] = v.z; sm[kr * 65 + n4 + 3] = v.w;
    }
    __syncthreads();
#pragma unroll
    for (int c = 0; c < 4; ++c) {
        int i = t + c * 256;
        int nr = i >> 4;
        int k4 = (i & 15) << 2;
        ushort4 o;
        o.x = f2bf(sm[(k4 + 0) * 65 + nr]);
        o.y = f2bf(sm[(k4 + 1) * 65 + nr]);
        o.z = f2bf(sm[(k4 + 2) * 65 + nr]);
        o.w = f2bf(sm[(k4 + 3) * 65 + nr]);
        *(ushort4*)(cls_wT + (size_t)(nt * 64 + nr) * HH + kt * 64 + k4) = o;
    }
}

// ---------------------------------------------------------------------------
// k_g1: partM[z][4096][256] = fc_w[:, z-slice] @ cls_w[z-slice, :]  (f32)
// grid (128, 4): tile 32m x 256n, K per z = 256 (4 iters of BK=64).
// 512 blocks = 2/CU. B staged as raw bf16 copies from cls_wT.
// ---------------------------------------------------------------------------
__global__ __launch_bounds__(256) void k_g1(const float* __restrict__ fc_w,
                                            const unsigned short* __restrict__ Bt,
                                            float* __restrict__ partM)
{
    __shared__ short As[32][72];
    __shared__ short Bs[256][72];
    const int t = threadIdx.x;
    const int lane = t & 63;
    const int wid = t >> 6;
    const int bm = blockIdx.x * 32;
    const int z = blockIdx.y;
    const int kbase = z * (HH / ZS1);   // 256

    f32x4 acc[2][4] = {};

    for (int k0 = kbase; k0 < kbase + HH / ZS1; k0 += 64) {
        // A tile 32x64: fc_w f32 -> bf16 (2 float4 per thread)
#pragma unroll
        for (int c = 0; c < 2; ++c) {
            int i = t + c * 256;
            int row = i >> 4;              // 0..31
            int k4 = (i & 15) << 2;
            float4 v = *(const float4*)(fc_w + (size_t)(bm + row) * HH + k0 + k4);
            ushort4 o;
            o.x = f2bf(v.x); o.y = f2bf(v.y); o.z = f2bf(v.z); o.w = f2bf(v.w);
            *(ushort4*)&As[row][k4] = o;
        }
        // B tile 256x64: straight bf16 copy (8 uint4 per thread)
#pragma unroll
        for (int c = 0; c < 8; ++c) {
            int i = t + c * 256;
            int n = i >> 3;                // 0..255
            int k8 = (i & 7) << 3;
            *(uint4*)&Bs[n][k8] =
                *(const uint4*)(Bt + (size_t)n * HH + k0 + k8);
        }
        __syncthreads();
#pragma unroll
        for (int ks = 0; ks < 2; ++ks) {
            int kk = ks * 32 + ((lane >> 4) << 3);
            int ar = lane & 15;
            bf16x8 a0 = *(const bf16x8*)&As[ar][kk];
            bf16x8 a1 = *(const bf16x8*)&As[16 + ar][kk];
#pragma unroll
            for (int fn = 0; fn < 4; ++fn) {
                bf16x8 b = *(const bf16x8*)&Bs[wid * 64 + fn * 16 + ar][kk];
                acc[0][fn] = __builtin_amdgcn_mfma_f32_16x16x32_bf16(a0, b, acc[0][fn], 0, 0, 0);
                acc[1][fn] = __builtin_amdgcn_mfma_f32_16x16x32_bf16(a1, b, acc[1][fn], 0, 0, 0);
            }
        }
        __syncthreads();
    }
#pragma unroll
    for (int fm = 0; fm < 2; ++fm)
#pragma unroll
        for (int fn = 0; fn < 4; ++fn) {
            int gm0 = bm + fm * 16 + ((lane >> 4) << 2);
            int gn = wid * 64 + fn * 16 + (lane & 15);
#pragma unroll
            for (int r = 0; r < 4; ++r)
                partM[((size_t)z * K2 + gm0 + r) * NPAD + gn] = acc[fm][fn][r];
        }
}

// ---------------------------------------------------------------------------
// k_red: blocks [0,256): Mt[n][m] bf16 = sum_z partM[z][m][n] (64x64 tiles,
//        LDS transpose). blocks [256,281): bvec = fc_b @ cls_w + cls_b.
// ---------------------------------------------------------------------------
__global__ __launch_bounds__(256) void k_red(const float* __restrict__ partM,
                                             const float* __restrict__ cls_w,
                                             const float* __restrict__ fc_b,
                                             const float* __restrict__ cls_b,
                                             unsigned short* __restrict__ Mt,
                                             float* __restrict__ bvec)
{
    __shared__ float sm[64][69];
    __shared__ float red[256];
    const int bx = blockIdx.x;
    const int t = threadIdx.x;

    if (bx >= 256) {
        const int bb = bx - 256;          // 0..24
        int c8 = t & 7;
        int hs = t >> 3;
        int c = bb * 8 + c8;              // < 200
        float acc = 0.f;
        for (int h = hs; h < HH; h += 32)
            acc += fc_b[h] * cls_w[(size_t)h * CC + c];
        red[t] = acc;
        __syncthreads();
        for (int s = 128; s >= 8; s >>= 1) {
            if (t < s) red[t] += red[t + s];
            __syncthreads();
        }
        if (t < 8) bvec[c] = red[t] + cls_b[c];
        return;
    }

    const int bm = (bx >> 2) * 64;        // m-tile (4096)
    const int bn = (bx & 3) * 64;         // n-tile (256)
#pragma unroll
    for (int c = 0; c < 4; ++c) {
        int i = t + c * 256;
        int mr = i >> 4;                  // 0..63
        int n4 = (i & 15) << 2;
        float4 s = {0.f, 0.f, 0.f, 0.f};
#pragma unroll
        for (int z = 0; z < ZS1; ++z) {
            float4 v = *(const float4*)(partM +
                ((size_t)z * K2 + bm + mr) * NPAD + bn + n4);
            s.x += v.x; s.y += v.y; s.z += v.z; s.w += v.w;
        }
        sm[mr][n4 + 0] = s.x; sm[mr][n4 + 1] = s.y;
        sm[mr][n4 + 2] = s.z; sm[mr][n4 + 3] = s.w;
    }
    __syncthreads();
#pragma unroll
    for (int c = 0; c < 4; ++c) {
        int i = t + c * 256;
        int nr = i >> 4;                  // 0..63
        int m4 = (i & 15) << 2;
        ushort4 o;
        o.x = f2bf(sm[m4 + 0][nr]);
        o.y = f2bf(sm[m4 + 1][nr]);
        o.z = f2bf(sm[m4 + 2][nr]);
        o.w = f2bf(sm[m4 + 3][nr]);
        *(ushort4*)(Mt + (size_t)(bn + nr) * K2 + bm + m4) = o;
    }
}

// ---------------------------------------------------------------------------
// k_pq: standalone, zero LDS. pq[b][0:D]=sum_u s*pf, pq[b][D:2D]=sum_u pf.
// ---------------------------------------------------------------------------
__global__ __launch_bounds__(256) void k_pq(const float* __restrict__ pf,
                                            const float* __restrict__ cdds,
                                            unsigned short* __restrict__ pq)
{
    const int bid = blockIdx.x;
    const int b = bid >> 1;
    const int d = ((bid & 1) << 10) + (threadIdx.x << 2);

    const float* base = pf + (size_t)b * NNODE * DD + d;
    float4 v0 = *(const float4*)(base + 0 * DD);
    float4 v1 = *(const float4*)(base + 1 * DD);
    float4 v2 = *(const float4*)(base + 2 * DD);
    float4 v3 = *(const float4*)(base + 3 * DD);
    float4 v4 = *(const float4*)(base + 4 * DD);
    float4 v5 = *(const float4*)(base + 5 * DD);

    float sv[NNODE];
    compute_s_wave(cdds, b, sv);

    float4 q;
    q.x = v0.x + v1.x + v2.x + v3.x + v4.x + v5.x;
    q.y = v0.y + v1.y + v2.y + v3.y + v4.y + v5.y;
    q.z = v0.z + v1.z + v2.z + v3.z + v4.z + v5.z;
    q.w = v0.w + v1.w + v2.w + v3.w + v4.w + v5.w;

    float4 p = {0.f, 0.f, 0.f, 0.f};
    p.x = fmaf(sv[0], v0.x, p.x); p.y = fmaf(sv[0], v0.y, p.y);
    p.z = fmaf(sv[0], v0.z, p.z); p.w = fmaf(sv[0], v0.w, p.w);
    p.x = fmaf(sv[1], v1.x, p.x); p.y = fmaf(sv[1], v1.y, p.y);
    p.z = fmaf(sv[1], v1.z, p.z); p.w = fmaf(sv[1], v1.w, p.w);
    p.x = fmaf(sv[2], v2.x, p.x); p.y = fmaf(sv[2], v2.y, p.y);
    p.z = fmaf(sv[2], v2.z, p.z); p.w = fmaf(sv[2], v2.w, p.w);
    p.x = fmaf(sv[3], v3.x, p.x); p.y = fmaf(sv[3], v3.y, p.y);
    p.z = fmaf(sv[3], v3.z, p.z); p.w = fmaf(sv[3], v3.w, p.w);
    p.x = fmaf(sv[4], v4.x, p.x); p.y = fmaf(sv[4], v4.y, p.y);
    p.z = fmaf(sv[4], v4.z, p.z); p.w = fmaf(sv[4], v4.w, p.w);
    p.x = fmaf(sv[5], v5.x, p.x); p.y = fmaf(sv[5], v5.y, p.y);
    p.z = fmaf(sv[5], v5.z, p.z); p.w = fmaf(sv[5], v5.w, p.w);

    unsigned short* o = pq + (size_t)b * K2;
    ushort4 pb, qb;
    pb.x = f2bf(p.x); pb.y = f2bf(p.y); pb.z = f2bf(p.z); pb.w = f2bf(p.w);
    qb.x = f2bf(q.x); qb.y = f2bf(q.y); qb.z = f2bf(q.z); qb.w = f2bf(q.w);
    *(ushort4*)(o + d) = pb;
    *(ushort4*)(o + DD + d) = qb;
}

// ---------------------------------------------------------------------------
// GEMM2: part[z][2048][256] = pq @ Mt^T partial (bf16 MFMA, split-K=16)
// grid (32, 16) = 512 blocks. Tile 64 x 256, K per z = 256.
// ---------------------------------------------------------------------------
__global__ __launch_bounds__(256) void k_gemm2(const unsigned short* __restrict__ A,
                                               const unsigned short* __restrict__ Bt,
                                               float* __restrict__ part)
{
    __shared__ short As[64][72];    // 9.2 KB
    __shared__ short Bs[256][72];   // 36.9 KB
    const int t = threadIdx.x;
    const int lane = t & 63;
    const int wid = t >> 6;
    const int wr = wid >> 1, wc = wid & 1;
    const int bm = blockIdx.x * 64;
    const int z = blockIdx.y;
    const int kbase = z * (K2 / ZS2);   // 256 per z

    f32x4 acc[2][8] = {};

    for (int k0 = kbase; k0 < kbase + K2 / ZS2; k0 += 64) {
#pragma unroll
        for (int c = 0; c < 2; ++c) {
            int i = t + c * 256;
            int row = i >> 3;
            int k8 = (i & 7) << 3;
            *(uint4*)&As[row][k8] =
                *(const uint4*)(A + (size_t)(bm + row) * K2 + k0 + k8);
        }
#pragma unroll
        for (int c = 0; c < 8; ++c) {
            int i = t + c * 256;
            int n = i >> 3;
            int k8 = (i & 7) << 3;
            *(uint4*)&Bs[n][k8] =
                *(const uint4*)(Bt + (size_t)n * K2 + k0 + k8);
        }
        __syncthreads();
#pragma unroll
        for (int ks = 0; ks < 2; ++ks) {
            int kk = ks * 32 + ((lane >> 4) << 3);
            int ar = lane & 15;
            bf16x8 a0 = *(const bf16x8*)&As[wr * 32 + ar][kk];
            bf16x8 a1 = *(const bf16x8*)&As[wr * 32 + 16 + ar][kk];
#pragma unroll
            for (int fn = 0; fn < 8; ++fn) {
                bf16x8 b = *(const bf16x8*)&Bs[wc * 128 + fn * 16 + ar][kk];
                acc[0][fn] = __builtin_amdgcn_mfma_f32_16x16x32_bf16(a0, b, acc[0][fn], 0, 0, 0);
                acc[1][fn] = __builtin_amdgcn_mfma_f32_16x16x32_bf16(a1, b, acc[1][fn], 0, 0, 0);
            }
        }
        __syncthreads();
    }
#pragma unroll
    for (int fm = 0; fm < 2; ++fm)
#pragma unroll
        for (int fn = 0; fn < 8; ++fn) {
            int gm0 = bm + wr * 32 + fm * 16 + ((lane >> 4) << 2);
            int gn = wc * 128 + fn * 16 + (lane & 15);
#pragma unroll
            for (int r = 0; r < 4; ++r)
                part[((size_t)z * NB + gm0 + r) * NPAD + gn] = acc[fm][fn][r];
        }
}

// ---------------------------------------------------------------------------
// out[b,c] = (sum_z part[z][b][c]) / 6 + bvec[c]
// ---------------------------------------------------------------------------
__global__ __launch_bounds__(256) void k_combine(const float* __restrict__ part,
                                                 const float* __restrict__ bvec,
                                                 float* __restrict__ out)
{
    int idx = blockIdx.x * blockDim.x + threadIdx.x;
    if (idx >= NB * CC) return;
    int b = idx / CC;
    int c = idx - b * CC;
    float s = 0.f;
#pragma unroll
    for (int z = 0; z < ZS2; ++z)
        s += part[((size_t)z * NB + b) * NPAD + c];
    out[idx] = s * (1.f / 6.f) + bvec[c];
}

// ---------------------------------------------------------------------------
extern "C" void kernel_launch(void* const* d_in, const int* in_sizes, int n_in,
                              void* d_out, int out_size, void* d_ws, size_t ws_size,
                              hipStream_t stream)
{
    const float* part_feats = (const float*)d_in[0];
    const float* cdds = (const float*)d_in[1];
    const float* fc_w = (const float*)d_in[2];   // (4096, 1024)
    const float* fc_b = (const float*)d_in[3];   // (1024,)
    const float* cls_w = (const float*)d_in[4];  // (1024, 200)
    const float* cls_b = (const float*)d_in[5];  // (200,)
    float* out = (float*)d_out;                  // (2048, 200)

    char* ws = (char*)d_ws;
    size_t off = 0;
    unsigned short* pq = (unsigned short*)(ws + off);     off += (size_t)NB * K2 * 2;         // 16.8 MB
    unsigned short* Mt = (unsigned short*)(ws + off);     off += (size_t)NPAD * K2 * 2;       // 2.1 MB
    unsigned short* cls_wT = (unsigned short*)(ws + off); off += (size_t)NPAD * HH * 2;       // 0.5 MB
    float* partM = (float*)(ws + off);                    off += (size_t)ZS1 * K2 * NPAD * 4; // 16.8 MB
    float* part = (float*)(ws + off);                     off += (size_t)ZS2 * NB * NPAD * 4; // 33.6 MB
    float* bvec = (float*)(ws + off);                     off += 256 * 4;

    // 1. cls_w -> cls_wT bf16 (transposed, padded)
    k_cvt<<<dim3(64), dim3(256), 0, stream>>>(cls_w, cls_wT);
    // 2. pq streaming (independent of 1)
    k_pq<<<dim3(NB * 2), dim3(256), 0, stream>>>(part_feats, cdds, pq);
    // 3. fc_w @ cls_wT partials, split-K=4, 512 blocks
    k_g1<<<dim3(K2 / 32, ZS1), dim3(256), 0, stream>>>(fc_w, cls_wT, partM);
    // 4. reduce partials -> Mt bf16 (+ bvec)
    k_red<<<dim3(256 + 25), dim3(256), 0, stream>>>(partM, cls_w, fc_b, cls_b, Mt, bvec);
    // 5. pq @ Mt^T partials, split-K=16
    k_gemm2<<<dim3(NB / 64, ZS2), dim3(256), 0, stream>>>(pq, Mt, part);
    // 6. combine + scale + bias
    k_combine<<<dim3((NB * CC + 255) / 256), dim3(256), 0, stream>>>(part, bvec, out);
}